// Round 10
// baseline (487.821 us; speedup 1.0000x reference)
//
#include <hip/hip_runtime.h>
#include <math.h>

#define S_LEN  4096
#define BATCH  4
#define DMODEL 1024
#define NHEADS 16
#define DHEAD  64
#define WIN    128

typedef _Float16 half8   __attribute__((ext_vector_type(8)));
typedef _Float16 half4_t __attribute__((ext_vector_type(4)));
typedef float    floatx4 __attribute__((ext_vector_type(4)));

__device__ __forceinline__ void gload16(const void* g, void* l) {
    __builtin_amdgcn_global_load_lds(
        (const __attribute__((address_space(1))) void*)g,
        (__attribute__((address_space(3))) void*)l, 16, 0, 0);
}

// ---------------- fp32 -> fp16 conversion (memory-bound) ----------------
__global__ __launch_bounds__(256)
void cvt_f32_f16(const float4* __restrict__ in, half4_t* __restrict__ out, int n4) {
    for (int i = blockIdx.x * blockDim.x + threadIdx.x; i < n4;
         i += gridDim.x * blockDim.x) {
        const float4 a = in[i];
        half4_t h;
        h[0] = (_Float16)a.x; h[1] = (_Float16)a.y;
        h[2] = (_Float16)a.z; h[3] = (_Float16)a.w;
        out[i] = h;
    }
}

__global__ __launch_bounds__(256)
void cvt4_f32_f16(const float4* __restrict__ w0, const float4* __restrict__ w1,
                  const float4* __restrict__ w2, const float4* __restrict__ w3,
                  half4_t* __restrict__ o0, half4_t* __restrict__ o1,
                  half4_t* __restrict__ o2, half4_t* __restrict__ o3, int n4) {
    const float4* in  = blockIdx.y == 0 ? w0 : (blockIdx.y == 1 ? w1 : (blockIdx.y == 2 ? w2 : w3));
    half4_t*      out = blockIdx.y == 0 ? o0 : (blockIdx.y == 1 ? o1 : (blockIdx.y == 2 ? o2 : o3));
    for (int i = blockIdx.x * blockDim.x + threadIdx.x; i < n4;
         i += gridDim.x * blockDim.x) {
        const float4 a = in[i];
        half4_t h;
        h[0] = (_Float16)a.x; h[1] = (_Float16)a.y;
        h[2] = (_Float16)a.z; h[3] = (_Float16)a.w;
        out[i] = h;
    }
}

// ---------------- f16 MFMA GEMM, 256x256 tile, BK=64, 3-phase/K-tile ------
// Snake quadrants (00)->(01)->(11)+(10); lo-fragments ping-pong (a_l0/a_l1)
// so the cross-tile tail reads are register-independent of the in-flight
// MFMAs and overlap them (r9's serial tail region removed). 3 barriers/tile.
// Stages: P2: B1(t+2)+A0(t+2); P3: A1(t+2)+B0(t+2). vmcnt(8) at P3-start
// (12 outstanding, keep newest 8 = t+2's) forces tile t+1 fully landed
// before its tail reads. WAR: each stage >=1 barrier after its region's
// reader drain (P1-PHEND / P2-PHEND / t-1 P3-PHEND respectively).
// LDS XOR swizzle slot^=(row&7); linear gload_lds dest + pre-swizzled src.
// MODE 0: f16 out; slab z=n0>>10: z=0,1 -> [B,H,S,Dh]; z=2 -> V^T [B,H,Dh,S].
// MODE 1: fp32 flat [M,1024], bias B0.
template<int MODE, int NTN>
__global__ __launch_bounds__(512)
void gemm3p(const _Float16* __restrict__ A, const _Float16* __restrict__ W,
            const float* __restrict__ B0, const float* __restrict__ B1,
            const float* __restrict__ B2, void* __restrict__ out_base)
{
    constexpr int K  = DMODEL;
    constexpr int nt = K / 64;                   // 16 K-tiles (even)
    const int bid  = blockIdx.x;
    const int nwg8 = (64 * NTN) >> 3;
    const int swz  = (bid & 7) * nwg8 + (bid >> 3);
    const int i0   = (swz / NTN) * 256;
    const int n0   = (swz % NTN) * 256;

    __shared__ _Float16 As[4][128 * 64];         // [parity*2 + half]
    __shared__ _Float16 Bs[4][128 * 64];

    const int tid  = threadIdx.x;
    const int lane = tid & 63;
    const int wid  = tid >> 6;
    const int wr   = wid >> 2;
    const int wc   = wid & 3;
    const int fr   = lane & 15;
    const int fh   = lane >> 4;
    const int sw8  = fr & 7;
    const int ok0  = ((fh) ^ sw8) * 8;
    const int ok1  = ((4 + fh) ^ sw8) * 8;
    const int arow = (wr * 16 + fr) * 64;
    const int brow = (wc * 16 + fr) * 64;

    const int srow = tid >> 3;
    const int ssw  = ((tid & 7) ^ (srow & 7)) << 3;
    const _Float16* baseA = A + (size_t)(i0 + srow) * K + ssw;
    const _Float16* baseB = W + (size_t)(n0 + srow) * K + ssw;
    const int ldso = tid * 8;

    floatx4 acc[8][4];
    #pragma unroll
    for (int mi = 0; mi < 8; ++mi)
        #pragma unroll
        for (int ni = 0; ni < 4; ++ni) acc[mi][ni] = (floatx4)0.f;

    half8 a_l0[4][2], a_l1[4][2], b_l0[2][2], b_l1[2][2];  // lo frag ping-pong
    half8 a_hi[4][2], b_hi[2][2];

#define ST_A(TT, H)                                                          \
    do {                                                                     \
        _Float16* d_ = &As[(((TT) & 1) << 1) | (H)][ldso];                   \
        const _Float16* s_ = baseA + (size_t)((H) * 128) * K + (TT) * 64;    \
        gload16(s_, d_);                                                     \
        gload16(s_ + (size_t)64 * K, d_ + 4096);                             \
    } while (0)
#define ST_B(TT, H)                                                          \
    do {                                                                     \
        _Float16* d_ = &Bs[(((TT) & 1) << 1) | (H)][ldso];                   \
        const _Float16* s_ = baseB + (size_t)((H) * 128) * K + (TT) * 64;    \
        gload16(s_, d_);                                                     \
        gload16(s_ + (size_t)64 * K, d_ + 4096);                             \
    } while (0)
#define RD_A(DST, DB, H)                                                     \
    _Pragma("unroll")                                                        \
    for (int mi = 0; mi < 4; ++mi) {                                         \
        DST[mi][0] = *(const half8*)&As[(DB) | (H)][arow + mi * 2048 + ok0]; \
        DST[mi][1] = *(const half8*)&As[(DB) | (H)][arow + mi * 2048 + ok1]; \
    }
#define RD_B(DST, DB, H)                                                     \
    _Pragma("unroll")                                                        \
    for (int ni = 0; ni < 2; ++ni) {                                         \
        DST[ni][0] = *(const half8*)&Bs[(DB) | (H)][brow + ni * 4096 + ok0]; \
        DST[ni][1] = *(const half8*)&Bs[(DB) | (H)][brow + ni * 4096 + ok1]; \
    }
#define MFMA16(MB, NB, AA, BB)                                               \
    __builtin_amdgcn_s_setprio(1);                                           \
    _Pragma("unroll")                                                        \
    for (int kc = 0; kc < 2; ++kc)                                           \
        _Pragma("unroll")                                                    \
        for (int mi = 0; mi < 4; ++mi)                                       \
            _Pragma("unroll")                                                \
            for (int ni = 0; ni < 2; ++ni)                                   \
                acc[MB + mi][NB + ni] = __builtin_amdgcn_mfma_f32_16x16x32_f16( \
                    AA[mi][kc], BB[ni][kc], acc[MB + mi][NB + ni], 0, 0, 0); \
    __builtin_amdgcn_s_setprio(0);
#define PHEND                                                                \
    asm volatile("s_waitcnt lgkmcnt(0)" ::: "memory");                       \
    __builtin_amdgcn_sched_barrier(0);                                       \
    __builtin_amdgcn_s_barrier();

// One K-tile: 3 phases. CUR = this tile's lo frags; NXT = next tile's.
#define TILE_BODY(T, D2, DN, ALc, BLc, ALn, BLn)                             \
    {                                                                        \
        const bool st = (T) + 2 < nt;                                        \
        /* P1: q(0,0) */                                                     \
        RD_B(b_hi, D2, 1);                                                   \
        MFMA16(0, 0, ALc, BLc);                                              \
        PHEND;                                                               \
        /* P2: q(0,1) */                                                     \
        RD_A(a_hi, D2, 1);                                                   \
        if (st) { ST_B((T) + 2, 1); ST_A((T) + 2, 0); }                      \
        MFMA16(0, 2, ALc, b_hi);                                             \
        PHEND;                                                               \
        /* P3: q(1,1)+q(1,0); tail reads overlap MFMA */                     \
        if (st) { ST_A((T) + 2, 1); ST_B((T) + 2, 0); }                      \
        if (st) {                                                            \
            asm volatile("s_waitcnt vmcnt(8)" ::: "memory");                 \
        } else if ((T) + 1 < nt) {                                           \
            asm volatile("s_waitcnt vmcnt(0)" ::: "memory");                 \
        }                                                                    \
        if ((T) + 1 < nt) { RD_A(ALn, DN, 0); RD_B(BLn, DN, 0); }            \
        MFMA16(4, 2, a_hi, b_hi);                                            \
        MFMA16(4, 0, a_hi, BLc);                                             \
        PHEND;                                                               \
    }

    // ---- prologue: stage t0 + t1 fully; force t0; read t0 lo frags ----
    ST_B(0, 1); ST_A(0, 0); ST_A(0, 1); ST_B(0, 0);
    ST_B(1, 1); ST_A(1, 0); ST_A(1, 1); ST_B(1, 0);
    asm volatile("s_waitcnt vmcnt(8)" ::: "memory");
    __builtin_amdgcn_sched_barrier(0);
    __builtin_amdgcn_s_barrier();
    RD_A(a_l0, 0, 0); RD_B(b_l0, 0, 0);
    asm volatile("s_waitcnt lgkmcnt(0)" ::: "memory");
    __builtin_amdgcn_sched_barrier(0);

    for (int t = 0; t < nt; t += 2) {
        TILE_BODY(t,     0, 2, a_l0, b_l0, a_l1, b_l1);
        TILE_BODY(t + 1, 2, 0, a_l1, b_l1, a_l0, b_l0);
    }
#undef ST_A
#undef ST_B
#undef RD_A
#undef RD_B
#undef MFMA16
#undef PHEND
#undef TILE_BODY

    // ---- epilogue: C/D layout col=lane&15, row=(lane>>4)*4+reg ----
    const int z  = (MODE == 0) ? (n0 >> 10) : 0;
    const float* bz = (MODE == 1) ? B0 : (z == 0 ? B0 : (z == 1 ? B1 : B2));

    #pragma unroll
    for (int ni = 0; ni < 4; ++ni) {
        const int gc   = n0 + ni * 64 + wc * 16 + fr;
        const int gcol = gc & (DMODEL - 1);
        const float bv = bz[gcol];
        #pragma unroll
        for (int mi = 0; mi < 8; ++mi) {
            const int gr = i0 + mi * 32 + wr * 16 + fh * 4;
            const floatx4 v = acc[mi][ni];
            if (MODE == 0) {
                _Float16* outh = (_Float16*)out_base
                               + (size_t)z * ((size_t)16384 * DMODEL);
                const int bb = gr >> 12;
                const int sp = gr & (S_LEN - 1);
                const int hh = gcol >> 6;
                const int dh = gcol & 63;
                if (z < 2) {
                    #pragma unroll
                    for (int r = 0; r < 4; ++r)
                        outh[((((size_t)(bb * NHEADS + hh)) * S_LEN + sp + r) << 6) + dh] =
                            (_Float16)(v[r] + bv);
                } else {
                    half4_t hv;
                    hv[0] = (_Float16)(v[0] + bv); hv[1] = (_Float16)(v[1] + bv);
                    hv[2] = (_Float16)(v[2] + bv); hv[3] = (_Float16)(v[3] + bv);
                    *(half4_t*)&outh[(((size_t)(bb * NHEADS + hh)) * DHEAD + dh) * S_LEN + sp] = hv;
                }
            } else {
                float* out = (float*)out_base;
                #pragma unroll
                for (int r = 0; r < 4; ++r)
                    out[(size_t)(gr + r) * DMODEL + gcol] = v[r] + bv;
            }
        }
    }
}

// ---------------- MFMA windowed attention, exact prefix-max scan ----------
// qh,kh: [B,H,S,Dh] f16; vth: [B,H,Dh,S] f16; o: [B,S,H,Dh] f16.
__global__ __launch_bounds__(256)
void attn_mfma(const _Float16* __restrict__ qh_, const _Float16* __restrict__ kh_,
               const _Float16* __restrict__ vth_, _Float16* __restrict__ o)
{
    __shared__ __align__(16) _Float16 Qs[64 * 64];
    __shared__ __align__(16) _Float16 Ks[64 * 64];
    __shared__ __align__(16) _Float16 Vt[64 * 64];
    __shared__ __align__(16) float    SP[64 * 68];
    __shared__ __align__(16) _Float16 P16[64 * 64];
    __shared__ float CM[64 * 4];
    __shared__ float TSs[64 * 4];
    __shared__ float Mq[64];
    __shared__ float Tq[64];

    const int tid   = threadIdx.x;
    const int lane  = tid & 63;
    const int w     = tid >> 6;
    const int qbase = blockIdx.x * 64;
    const int head  = blockIdx.y, b = blockIdx.z;
    const size_t bh = (size_t)(b * NHEADS + head);

    const _Float16* qg = qh_  + bh * (size_t)(S_LEN * DHEAD);
    const _Float16* kg = kh_  + bh * (size_t)(S_LEN * DHEAD);
    const _Float16* vg = vth_ + bh * (size_t)(DHEAD * S_LEN);

    const int fr = lane & 15;
    const int fh = lane >> 4;

    #pragma unroll
    for (int rep = 0; rep < 2; ++rep) {
        const int c = tid + 256 * rep;
        const int row = c >> 3, sll = c & 7;
        gload16(qg + (size_t)(qbase + row) * 64 + (size_t)((sll ^ (row & 7)) * 8),
                Qs + (size_t)c * 8);
    }
    if (tid < 64) { Mq[tid] = -INFINITY; Tq[tid] = 0.f; }

    floatx4 Oacc[4];
    #pragma unroll
    for (int ni = 0; ni < 4; ++ni) Oacc[ni] = (floatx4)0.f;

    for (int c = 0; c < 5; ++c) {
        const int jlo = qbase - WIN + c * 64;
        if (jlo < 0 || jlo >= S_LEN) continue;
        const int base_rel = jlo - qbase + WIN;

        __syncthreads();

        #pragma unroll
        for (int rep = 0; rep < 2; ++rep) {
            const int cc = tid + 256 * rep;
            const int row = cc >> 3, sll = cc & 7;
            gload16(kg + (size_t)(jlo + row) * 64 + (size_t)((sll ^ (row & 7)) * 8),
                    Ks + (size_t)cc * 8);
            gload16(vg + (size_t)row * S_LEN + jlo + (size_t)((sll ^ (row & 7)) * 8),
                    Vt + (size_t)cc * 8);
        }
        __syncthreads();

        {
            floatx4 acc[4];
            #pragma unroll
            for (int ni = 0; ni < 4; ++ni) acc[ni] = (floatx4)0.f;
            half8 a[2];
            #pragma unroll
            for (int kc = 0; kc < 2; ++kc) {
                const int row = 16 * w + fr;
                a[kc] = *(const half8*)&Qs[row * 64 + ((fh + 4 * kc) ^ (row & 7)) * 8];
            }
            #pragma unroll
            for (int ni = 0; ni < 4; ++ni)
                #pragma unroll
                for (int kc = 0; kc < 2; ++kc) {
                    const int tr = 16 * ni + fr;
                    half8 bf = *(const half8*)&Ks[tr * 64 + ((fh + 4 * kc) ^ (tr & 7)) * 8];
                    acc[ni] = __builtin_amdgcn_mfma_f32_16x16x32_f16(a[kc], bf, acc[ni], 0, 0, 0);
                }
            #pragma unroll
            for (int ni = 0; ni < 4; ++ni)
                #pragma unroll
                for (int r = 0; r < 4; ++r)
                    SP[(16 * w + 4 * fh + r) * 68 + fr + 16 * ni] = acc[ni][r] * 0.125f;
        }
        __syncthreads();

        const int sq = lane;
        float sv[16], run[16];
        {
            float m_run = -INFINITY;
            #pragma unroll
            for (int u = 0; u < 4; ++u) {
                const float4 s4 = *(const float4*)&SP[sq * 68 + w * 16 + 4 * u];
                const float se[4] = {s4.x, s4.y, s4.z, s4.w};
                #pragma unroll
                for (int e = 0; e < 4; ++e) {
                    const int i = 4 * u + e;
                    const int rel = base_rel + 16 * w + i - sq;
                    const bool valid = (rel >= 0) && (rel <= 2 * WIN);
                    const float s = valid ? se[e] : -INFINITY;
                    sv[i] = s;
                    m_run = fmaxf(m_run, s);
                    run[i] = m_run;
                }
            }
            CM[sq * 4 + w] = m_run;
        }
        __syncthreads();

        {
            float pre = Mq[sq];
            if (w > 0) pre = fmaxf(pre, CM[sq * 4 + 0]);
            if (w > 1) pre = fmaxf(pre, CM[sq * 4 + 1]);
            if (w > 2) pre = fmaxf(pre, CM[sq * 4 + 2]);
            float tl = 0.f;
            _Float16 pf[16];
            #pragma unroll
            for (int i = 0; i < 16; ++i) {
                const float wv = fmaxf(pre, run[i]);
                const float p = (sv[i] != -INFINITY) ? __expf(sv[i] - wv) : 0.f;
                tl += p;
                pf[i] = (_Float16)p;
            }
            TSs[sq * 4 + w] = tl;
            #pragma unroll
            for (int u = 0; u < 2; ++u) {
                half8 h8;
                #pragma unroll
                for (int e = 0; e < 8; ++e) h8[e] = pf[8 * u + e];
                *(half8*)&P16[sq * 64 + ((2 * w + u) ^ (sq & 7)) * 8] = h8;
            }
        }
        __syncthreads();

        if (tid < 64) {
            const float mm = fmaxf(fmaxf(CM[tid * 4 + 0], CM[tid * 4 + 1]),
                                   fmaxf(CM[tid * 4 + 2], CM[tid * 4 + 3]));
            Mq[tid] = fmaxf(Mq[tid], mm);
            Tq[tid] += TSs[tid * 4 + 0] + TSs[tid * 4 + 1] + TSs[tid * 4 + 2] + TSs[tid * 4 + 3];
        }

        {
            half8 pa[2];
            #pragma unroll
            for (int kc = 0; kc < 2; ++kc) {
                const int row = 16 * w + fr;
                pa[kc] = *(const half8*)&P16[row * 64 + ((fh + 4 * kc) ^ (row & 7)) * 8];
            }
            #pragma unroll
            for (int ni = 0; ni < 4; ++ni)
                #pragma unroll
                for (int kc = 0; kc < 2; ++kc) {
                    const int dr = 16 * ni + fr;
                    half8 bf = *(const half8*)&Vt[dr * 64 + ((fh + 4 * kc) ^ (dr & 7)) * 8];
                    Oacc[ni] = __builtin_amdgcn_mfma_f32_16x16x32_f16(pa[kc], bf, Oacc[ni], 0, 0, 0);
                }
        }
    }

    __syncthreads();

    #pragma unroll
    for (int ni = 0; ni < 4; ++ni)
        #pragma unroll
        for (int r = 0; r < 4; ++r) {
            const int q  = 16 * w + 4 * fh + r;
            const float inv = 1.0f / Tq[q];
            o[((size_t)(b * S_LEN + qbase + q) * NHEADS + head) * DHEAD + fr + 16 * ni] =
                (_Float16)(Oacc[ni][r] * inv);
        }
}

extern "C" void kernel_launch(void* const* d_in, const int* in_sizes, int n_in,
                              void* d_out, int out_size, void* d_ws, size_t ws_size,
                              hipStream_t stream) {
    const float* x  = (const float*)d_in[0];
    const float* wq = (const float*)d_in[1];
    const float* bq = (const float*)d_in[2];
    const float* wk = (const float*)d_in[3];
    const float* bk = (const float*)d_in[4];
    const float* wv = (const float*)d_in[5];
    const float* bv = (const float*)d_in[6];
    const float* wo = (const float*)d_in[7];
    const float* bo = (const float*)d_in[8];

    const size_t BUF = (size_t)BATCH * S_LEN * DMODEL;   // 16,777,216 elems
    _Float16* xh  = (_Float16*)d_ws;
    _Float16* qh  = xh + BUF;
    _Float16* kh  = qh + BUF;       // qh/kh/vth consecutive (z-slab offset)
    _Float16* vth = kh + BUF;
    _Float16* oh  = vth + BUF;
    _Float16* wqh = oh + BUF;       // wqh/wkh/wvh consecutive = W_all [3072,1024]
    _Float16* wkh = wqh + DMODEL * DMODEL;
    _Float16* wvh = wkh + DMODEL * DMODEL;
    _Float16* woh = wvh + DMODEL * DMODEL;

    // 1) fp32 -> f16 conversions
    cvt_f32_f16<<<2048, 256, 0, stream>>>((const float4*)x, (half4_t*)xh, (int)(BUF / 4));
    cvt4_f32_f16<<<dim3(256, 4), 256, 0, stream>>>(
        (const float4*)wq, (const float4*)wk, (const float4*)wv, (const float4*)wo,
        (half4_t*)wqh, (half4_t*)wkh, (half4_t*)wvh, (half4_t*)woh,
        DMODEL * DMODEL / 4);

    // 2) fused QKV projection: [16384,1024] @ [3072,1024]^T
    gemm3p<0, 12><<<64 * 12, 512, 0, stream>>>(xh, wqh, bq, bk, bv, (void*)qh);

    // 3) MFMA windowed attention -> oh f16 [B,S,H,Dh]
    dim3 gattn(S_LEN / 64, NHEADS, BATCH);
    attn_mfma<<<gattn, 256, 0, stream>>>(qh, kh, vth, oh);

    // 4) output projection -> fp32 d_out
    gemm3p<1, 4><<<64 * 4, 512, 0, stream>>>(oh, woh, bo, bo, bo, d_out);
}

// Round 12
// 257.073 us; speedup vs baseline: 1.8976x; 1.8976x over previous
//
#include <hip/hip_runtime.h>
#include <math.h>

#define S_LEN  4096
#define BATCH  4
#define DMODEL 1024
#define NHEADS 16
#define DHEAD  64
#define WIN    128

typedef _Float16 half8   __attribute__((ext_vector_type(8)));
typedef _Float16 half4_t __attribute__((ext_vector_type(4)));
typedef float    floatx4 __attribute__((ext_vector_type(4)));

__device__ __forceinline__ void gload16(const void* g, void* l) {
    __builtin_amdgcn_global_load_lds(
        (const __attribute__((address_space(1))) void*)g,
        (__attribute__((address_space(3))) void*)l, 16, 0, 0);
}

// ---------------- fp32 -> fp16 conversion, one launch for x + 4 weights ---
// grid.y = 0 -> x (n4x float4s); grid.y = 1..4 -> weight y-1 (n4w each).
__global__ __launch_bounds__(256)
void cvt5_f32_f16(const float4* __restrict__ x,  half4_t* __restrict__ xo, int n4x,
                  const float4* __restrict__ w0, const float4* __restrict__ w1,
                  const float4* __restrict__ w2, const float4* __restrict__ w3,
                  half4_t* __restrict__ o0, half4_t* __restrict__ o1,
                  half4_t* __restrict__ o2, half4_t* __restrict__ o3, int n4w) {
    const int y = blockIdx.y;
    const float4* in  = y == 0 ? x  : (y == 1 ? w0 : (y == 2 ? w1 : (y == 3 ? w2 : w3)));
    half4_t*      out = y == 0 ? xo : (y == 1 ? o0 : (y == 2 ? o1 : (y == 3 ? o2 : o3)));
    const int n4 = y == 0 ? n4x : n4w;
    for (int i = blockIdx.x * blockDim.x + threadIdx.x; i < n4;
         i += gridDim.x * blockDim.x) {
        const float4 a = in[i];
        half4_t h;
        h[0] = (_Float16)a.x; h[1] = (_Float16)a.y;
        h[2] = (_Float16)a.z; h[3] = (_Float16)a.w;
        out[i] = h;
    }
}

// ---------------- f16 MFMA GEMM, 256x256 tile, BK=64, 4-phase/K-tile ------
// r9 champion schedule (verified 254us, absmax 0.00195) — byte-identical.
// Snake quadrant order (00)->(01)->(11)->(10); fragment reg-dbuf so each
// half is ds_read exactly ONCE per K-tile; 1 barrier/phase.
// Stages: P2: B1(t+2)+A0(t+2); P3: A1(t+2); P4: B0(t+2). vmcnt(8) at P4
// forces tile t+1 fully landed before its tail reads (oldest-first, m135).
// WAR: each stage >=1 barrier after its region's reader drain.
// LDS XOR swizzle slot^=(row&7); linear gload_lds dest + pre-swizzled src.
// MODE 0: f16 out; slab z=n0>>10: z=0,1 -> [B,H,S,Dh]; z=2 -> V^T [B,H,Dh,S].
// MODE 1: fp32 flat [M,1024], bias B0.
template<int MODE, int NTN>
__global__ __launch_bounds__(512)
void gemm8p(const _Float16* __restrict__ A, const _Float16* __restrict__ W,
            const float* __restrict__ B0, const float* __restrict__ B1,
            const float* __restrict__ B2, void* __restrict__ out_base)
{
    constexpr int K  = DMODEL;
    constexpr int nt = K / 64;                   // 16 K-tiles
    const int bid  = blockIdx.x;
    const int nwg8 = (64 * NTN) >> 3;
    const int swz  = (bid & 7) * nwg8 + (bid >> 3);
    const int i0   = (swz / NTN) * 256;
    const int n0   = (swz % NTN) * 256;

    __shared__ _Float16 As[4][128 * 64];         // [parity*2 + half]
    __shared__ _Float16 Bs[4][128 * 64];

    const int tid  = threadIdx.x;
    const int lane = tid & 63;
    const int wid  = tid >> 6;
    const int wr   = wid >> 2;
    const int wc   = wid & 3;
    const int fr   = lane & 15;
    const int fh   = lane >> 4;
    const int sw8  = fr & 7;
    const int ok0  = ((fh) ^ sw8) * 8;
    const int ok1  = ((4 + fh) ^ sw8) * 8;
    const int arow = (wr * 16 + fr) * 64;
    const int brow = (wc * 16 + fr) * 64;

    const int srow = tid >> 3;
    const int ssw  = ((tid & 7) ^ (srow & 7)) << 3;
    const _Float16* baseA = A + (size_t)(i0 + srow) * K + ssw;
    const _Float16* baseB = W + (size_t)(n0 + srow) * K + ssw;
    const int ldso = tid * 8;

    floatx4 acc[8][4];
    #pragma unroll
    for (int mi = 0; mi < 8; ++mi)
        #pragma unroll
        for (int ni = 0; ni < 4; ++ni) acc[mi][ni] = (floatx4)0.f;

    half8 a_lo[4][2], a_hi[4][2], b_lo[2][2], b_hi[2][2];

#define ST_A(TT, H)                                                          \
    do {                                                                     \
        _Float16* d_ = &As[(((TT) & 1) << 1) | (H)][ldso];                   \
        const _Float16* s_ = baseA + (size_t)((H) * 128) * K + (TT) * 64;    \
        gload16(s_, d_);                                                     \
        gload16(s_ + (size_t)64 * K, d_ + 4096);                             \
    } while (0)
#define ST_B(TT, H)                                                          \
    do {                                                                     \
        _Float16* d_ = &Bs[(((TT) & 1) << 1) | (H)][ldso];                   \
        const _Float16* s_ = baseB + (size_t)((H) * 128) * K + (TT) * 64;    \
        gload16(s_, d_);                                                     \
        gload16(s_ + (size_t)64 * K, d_ + 4096);                             \
    } while (0)
#define RD_A(DST, DB, H)                                                     \
    _Pragma("unroll")                                                        \
    for (int mi = 0; mi < 4; ++mi) {                                         \
        DST[mi][0] = *(const half8*)&As[(DB) | (H)][arow + mi * 2048 + ok0]; \
        DST[mi][1] = *(const half8*)&As[(DB) | (H)][arow + mi * 2048 + ok1]; \
    }
#define RD_B(DST, DB, H)                                                     \
    _Pragma("unroll")                                                        \
    for (int ni = 0; ni < 2; ++ni) {                                         \
        DST[ni][0] = *(const half8*)&Bs[(DB) | (H)][brow + ni * 4096 + ok0]; \
        DST[ni][1] = *(const half8*)&Bs[(DB) | (H)][brow + ni * 4096 + ok1]; \
    }
#define MFMA16(MB, NB, AA, BB)                                               \
    __builtin_amdgcn_s_setprio(1);                                           \
    _Pragma("unroll")                                                        \
    for (int kc = 0; kc < 2; ++kc)                                           \
        _Pragma("unroll")                                                    \
        for (int mi = 0; mi < 4; ++mi)                                       \
            _Pragma("unroll")                                                \
            for (int ni = 0; ni < 2; ++ni)                                   \
                acc[MB + mi][NB + ni] = __builtin_amdgcn_mfma_f32_16x16x32_f16( \
                    AA[mi][kc], BB[ni][kc], acc[MB + mi][NB + ni], 0, 0, 0); \
    __builtin_amdgcn_s_setprio(0);
#define PHEND                                                                \
    asm volatile("s_waitcnt lgkmcnt(0)" ::: "memory");                       \
    __builtin_amdgcn_sched_barrier(0);                                       \
    __builtin_amdgcn_s_barrier();

    // ---- prologue: stage t0 + t1 fully; force t0; first lo-frag reads ----
    ST_A(0, 0); ST_B(0, 0); ST_B(0, 1); ST_A(0, 1);
    ST_A(1, 0); ST_B(1, 1); ST_A(1, 1); ST_B(1, 0);
    asm volatile("s_waitcnt vmcnt(8)" ::: "memory");
    __builtin_amdgcn_sched_barrier(0);
    __builtin_amdgcn_s_barrier();
    RD_A(a_lo, 0, 0); RD_B(b_lo, 0, 0);
    asm volatile("s_waitcnt lgkmcnt(0)" ::: "memory");
    __builtin_amdgcn_sched_barrier(0);

    for (int t = 0; t < nt; ++t) {
        const int d2 = (t & 1) << 1;
        const bool st = (t + 2) < nt;
        // ---- P1: q(0,0); reads B1; NO stage (WAR-safe window for A[d2|0]) --
        RD_B(b_hi, d2, 1);
        MFMA16(0, 0, a_lo, b_lo);
        PHEND;
        // ---- P2: q(0,1); reads A1; stage B1(t+2) + A0(t+2) ----
        RD_A(a_hi, d2, 1);
        if (st) { ST_B(t + 2, 1); ST_A(t + 2, 0); }
        MFMA16(0, 2, a_lo, b_hi);
        PHEND;
        // ---- P3: q(1,1); stage A1(t+2) ----
        if (st) ST_A(t + 2, 1);
        MFMA16(4, 2, a_hi, b_hi);
        PHEND;
        // ---- P4: q(1,0) (b_lo kept from P1); stage B0(t+2); vmcnt ----
        if (st) ST_B(t + 2, 0);
        MFMA16(4, 0, a_hi, b_lo);
        if (st) {
            asm volatile("s_waitcnt vmcnt(8)" ::: "memory");
        } else if (t + 1 < nt) {
            asm volatile("s_waitcnt vmcnt(0)" ::: "memory");
        }
        __builtin_amdgcn_sched_barrier(0);
        __builtin_amdgcn_s_barrier();
        // ---- cross-tile q1 fragment reads (tile t+1) ----
        if (t + 1 < nt) {
            const int dn = ((t + 1) & 1) << 1;
            RD_A(a_lo, dn, 0); RD_B(b_lo, dn, 0);
            asm volatile("s_waitcnt lgkmcnt(0)" ::: "memory");
            __builtin_amdgcn_sched_barrier(0);
        }
    }
#undef ST_A
#undef ST_B
#undef RD_A
#undef RD_B
#undef MFMA16
#undef PHEND

    // ---- epilogue: C/D layout col=lane&15, row=(lane>>4)*4+reg ----
    const int z  = (MODE == 0) ? (n0 >> 10) : 0;
    const float* bz = (MODE == 1) ? B0 : (z == 0 ? B0 : (z == 1 ? B1 : B2));

    #pragma unroll
    for (int ni = 0; ni < 4; ++ni) {
        const int gc   = n0 + ni * 64 + wc * 16 + fr;
        const int gcol = gc & (DMODEL - 1);
        const float bv = bz[gcol];
        #pragma unroll
        for (int mi = 0; mi < 8; ++mi) {
            const int gr = i0 + mi * 32 + wr * 16 + fh * 4;
            const floatx4 v = acc[mi][ni];
            if (MODE == 0) {
                _Float16* outh = (_Float16*)out_base
                               + (size_t)z * ((size_t)16384 * DMODEL);
                const int bb = gr >> 12;
                const int sp = gr & (S_LEN - 1);
                const int hh = gcol >> 6;
                const int dh = gcol & 63;
                if (z < 2) {
                    #pragma unroll
                    for (int r = 0; r < 4; ++r)
                        outh[((((size_t)(bb * NHEADS + hh)) * S_LEN + sp + r) << 6) + dh] =
                            (_Float16)(v[r] + bv);
                } else {
                    half4_t hv;
                    hv[0] = (_Float16)(v[0] + bv); hv[1] = (_Float16)(v[1] + bv);
                    hv[2] = (_Float16)(v[2] + bv); hv[3] = (_Float16)(v[3] + bv);
                    *(half4_t*)&outh[(((size_t)(bb * NHEADS + hh)) * DHEAD + dh) * S_LEN + sp] = hv;
                }
            } else {
                float* out = (float*)out_base;
                #pragma unroll
                for (int r = 0; r < 4; ++r)
                    out[(size_t)(gr + r) * DMODEL + gcol] = v[r] + bv;
            }
        }
    }
}

// ---------------- MFMA windowed attention, exact prefix-max scan ----------
// qh,kh: [B,H,S,Dh] f16; vth: [B,H,Dh,S] f16; o: [B,S,H,Dh] f16.
__global__ __launch_bounds__(256)
void attn_mfma(const _Float16* __restrict__ qh_, const _Float16* __restrict__ kh_,
               const _Float16* __restrict__ vth_, _Float16* __restrict__ o)
{
    __shared__ __align__(16) _Float16 Qs[64 * 64];
    __shared__ __align__(16) _Float16 Ks[64 * 64];
    __shared__ __align__(16) _Float16 Vt[64 * 64];
    __shared__ __align__(16) float    SP[64 * 68];
    __shared__ __align__(16) _Float16 P16[64 * 64];
    __shared__ float CM[64 * 4];
    __shared__ float TSs[64 * 4];
    __shared__ float Mq[64];
    __shared__ float Tq[64];

    const int tid   = threadIdx.x;
    const int lane  = tid & 63;
    const int w     = tid >> 6;
    const int qbase = blockIdx.x * 64;
    const int head  = blockIdx.y, b = blockIdx.z;
    const size_t bh = (size_t)(b * NHEADS + head);

    const _Float16* qg = qh_  + bh * (size_t)(S_LEN * DHEAD);
    const _Float16* kg = kh_  + bh * (size_t)(S_LEN * DHEAD);
    const _Float16* vg = vth_ + bh * (size_t)(DHEAD * S_LEN);

    const int fr = lane & 15;
    const int fh = lane >> 4;

    #pragma unroll
    for (int rep = 0; rep < 2; ++rep) {
        const int c = tid + 256 * rep;
        const int row = c >> 3, sll = c & 7;
        gload16(qg + (size_t)(qbase + row) * 64 + (size_t)((sll ^ (row & 7)) * 8),
                Qs + (size_t)c * 8);
    }
    if (tid < 64) { Mq[tid] = -INFINITY; Tq[tid] = 0.f; }

    floatx4 Oacc[4];
    #pragma unroll
    for (int ni = 0; ni < 4; ++ni) Oacc[ni] = (floatx4)0.f;

    for (int c = 0; c < 5; ++c) {
        const int jlo = qbase - WIN + c * 64;
        if (jlo < 0 || jlo >= S_LEN) continue;
        const int base_rel = jlo - qbase + WIN;

        __syncthreads();

        #pragma unroll
        for (int rep = 0; rep < 2; ++rep) {
            const int cc = tid + 256 * rep;
            const int row = cc >> 3, sll = cc & 7;
            gload16(kg + (size_t)(jlo + row) * 64 + (size_t)((sll ^ (row & 7)) * 8),
                    Ks + (size_t)cc * 8);
            gload16(vg + (size_t)row * S_LEN + jlo + (size_t)((sll ^ (row & 7)) * 8),
                    Vt + (size_t)cc * 8);
        }
        __syncthreads();

        {
            floatx4 acc[4];
            #pragma unroll
            for (int ni = 0; ni < 4; ++ni) acc[ni] = (floatx4)0.f;
            half8 a[2];
            #pragma unroll
            for (int kc = 0; kc < 2; ++kc) {
                const int row = 16 * w + fr;
                a[kc] = *(const half8*)&Qs[row * 64 + ((fh + 4 * kc) ^ (row & 7)) * 8];
            }
            #pragma unroll
            for (int ni = 0; ni < 4; ++ni)
                #pragma unroll
                for (int kc = 0; kc < 2; ++kc) {
                    const int tr = 16 * ni + fr;
                    half8 bf = *(const half8*)&Ks[tr * 64 + ((fh + 4 * kc) ^ (tr & 7)) * 8];
                    acc[ni] = __builtin_amdgcn_mfma_f32_16x16x32_f16(a[kc], bf, acc[ni], 0, 0, 0);
                }
            #pragma unroll
            for (int ni = 0; ni < 4; ++ni)
                #pragma unroll
                for (int r = 0; r < 4; ++r)
                    SP[(16 * w + 4 * fh + r) * 68 + fr + 16 * ni] = acc[ni][r] * 0.125f;
        }
        __syncthreads();

        const int sq = lane;
        float sv[16], run[16];
        {
            float m_run = -INFINITY;
            #pragma unroll
            for (int u = 0; u < 4; ++u) {
                const float4 s4 = *(const float4*)&SP[sq * 68 + w * 16 + 4 * u];
                const float se[4] = {s4.x, s4.y, s4.z, s4.w};
                #pragma unroll
                for (int e = 0; e < 4; ++e) {
                    const int i = 4 * u + e;
                    const int rel = base_rel + 16 * w + i - sq;
                    const bool valid = (rel >= 0) && (rel <= 2 * WIN);
                    const float s = valid ? se[e] : -INFINITY;
                    sv[i] = s;
                    m_run = fmaxf(m_run, s);
                    run[i] = m_run;
                }
            }
            CM[sq * 4 + w] = m_run;
        }
        __syncthreads();

        {
            float pre = Mq[sq];
            if (w > 0) pre = fmaxf(pre, CM[sq * 4 + 0]);
            if (w > 1) pre = fmaxf(pre, CM[sq * 4 + 1]);
            if (w > 2) pre = fmaxf(pre, CM[sq * 4 + 2]);
            float tl = 0.f;
            _Float16 pf[16];
            #pragma unroll
            for (int i = 0; i < 16; ++i) {
                const float wv = fmaxf(pre, run[i]);
                const float p = (sv[i] != -INFINITY) ? __expf(sv[i] - wv) : 0.f;
                tl += p;
                pf[i] = (_Float16)p;
            }
            TSs[sq * 4 + w] = tl;
            #pragma unroll
            for (int u = 0; u < 2; ++u) {
                half8 h8;
                #pragma unroll
                for (int e = 0; e < 8; ++e) h8[e] = pf[8 * u + e];
                *(half8*)&P16[sq * 64 + ((2 * w + u) ^ (sq & 7)) * 8] = h8;
            }
        }
        __syncthreads();

        if (tid < 64) {
            const float mm = fmaxf(fmaxf(CM[tid * 4 + 0], CM[tid * 4 + 1]),
                                   fmaxf(CM[tid * 4 + 2], CM[tid * 4 + 3]));
            Mq[tid] = fmaxf(Mq[tid], mm);
            Tq[tid] += TSs[tid * 4 + 0] + TSs[tid * 4 + 1] + TSs[tid * 4 + 2] + TSs[tid * 4 + 3];
        }

        {
            half8 pa[2];
            #pragma unroll
            for (int kc = 0; kc < 2; ++kc) {
                const int row = 16 * w + fr;
                pa[kc] = *(const half8*)&P16[row * 64 + ((fh + 4 * kc) ^ (row & 7)) * 8];
            }
            #pragma unroll
            for (int ni = 0; ni < 4; ++ni)
                #pragma unroll
                for (int kc = 0; kc < 2; ++kc) {
                    const int dr = 16 * ni + fr;
                    half8 bf = *(const half8*)&Vt[dr * 64 + ((fh + 4 * kc) ^ (dr & 7)) * 8];
                    Oacc[ni] = __builtin_amdgcn_mfma_f32_16x16x32_f16(pa[kc], bf, Oacc[ni], 0, 0, 0);
                }
        }
    }

    __syncthreads();

    #pragma unroll
    for (int ni = 0; ni < 4; ++ni)
        #pragma unroll
        for (int r = 0; r < 4; ++r) {
            const int q  = 16 * w + 4 * fh + r;
            const float inv = 1.0f / Tq[q];
            o[((size_t)(b * S_LEN + qbase + q) * NHEADS + head) * DHEAD + fr + 16 * ni] =
                (_Float16)(Oacc[ni][r] * inv);
        }
}

extern "C" void kernel_launch(void* const* d_in, const int* in_sizes, int n_in,
                              void* d_out, int out_size, void* d_ws, size_t ws_size,
                              hipStream_t stream) {
    const float* x  = (const float*)d_in[0];
    const float* wq = (const float*)d_in[1];
    const float* bq = (const float*)d_in[2];
    const float* wk = (const float*)d_in[3];
    const float* bk = (const float*)d_in[4];
    const float* wv = (const float*)d_in[5];
    const float* bv = (const float*)d_in[6];
    const float* wo = (const float*)d_in[7];
    const float* bo = (const float*)d_in[8];

    const size_t BUF = (size_t)BATCH * S_LEN * DMODEL;   // 16,777,216 elems
    _Float16* xh  = (_Float16*)d_ws;
    _Float16* qh  = xh + BUF;
    _Float16* kh  = qh + BUF;       // qh/kh/vth consecutive (z-slab offset)
    _Float16* vth = kh + BUF;
    _Float16* oh  = vth + BUF;
    _Float16* wqh = oh + BUF;       // wqh/wkh/wvh consecutive = W_all [3072,1024]
    _Float16* wkh = wqh + DMODEL * DMODEL;
    _Float16* wvh = wkh + DMODEL * DMODEL;
    _Float16* woh = wvh + DMODEL * DMODEL;

    // 1) fp32 -> f16 conversions (single launch; y=0 x, y=1..4 weights)
    cvt5_f32_f16<<<dim3(512, 5), 256, 0, stream>>>(
        (const float4*)x, (half4_t*)xh, (int)(BUF / 4),
        (const float4*)wq, (const float4*)wk, (const float4*)wv, (const float4*)wo,
        (half4_t*)wqh, (half4_t*)wkh, (half4_t*)wvh, (half4_t*)woh,
        DMODEL * DMODEL / 4);

    // 2) fused QKV projection: [16384,1024] @ [3072,1024]^T
    gemm8p<0, 12><<<64 * 12, 512, 0, stream>>>(xh, wqh, bq, bk, bv, (void*)qh);

    // 3) MFMA windowed attention -> oh f16 [B,S,H,Dh]
    dim3 gattn(S_LEN / 64, NHEADS, BATCH);
    attn_mfma<<<gattn, 256, 0, stream>>>(qh, kh, vth, oh);

    // 4) output projection -> fp32 d_out
    gemm8p<1, 4><<<64 * 4, 512, 0, stream>>>(oh, woh, bo, bo, bo, d_out);
}

// Round 13
// 250.848 us; speedup vs baseline: 1.9447x; 1.0248x over previous
//
#include <hip/hip_runtime.h>
#include <math.h>

#define S_LEN  4096
#define BATCH  4
#define DMODEL 1024
#define NHEADS 16
#define DHEAD  64
#define WIN    128

typedef _Float16 half8   __attribute__((ext_vector_type(8)));
typedef _Float16 half4_t __attribute__((ext_vector_type(4)));
typedef float    floatx4 __attribute__((ext_vector_type(4)));

__device__ __forceinline__ void gload16(const void* g, void* l) {
    __builtin_amdgcn_global_load_lds(
        (const __attribute__((address_space(1))) void*)g,
        (__attribute__((address_space(3))) void*)l, 16, 0, 0);
}

// ---------------- fp32 -> fp16 conversion, one launch for x + 4 weights ---
__global__ __launch_bounds__(256)
void cvt5_f32_f16(const float4* __restrict__ x,  half4_t* __restrict__ xo, int n4x,
                  const float4* __restrict__ w0, const float4* __restrict__ w1,
                  const float4* __restrict__ w2, const float4* __restrict__ w3,
                  half4_t* __restrict__ o0, half4_t* __restrict__ o1,
                  half4_t* __restrict__ o2, half4_t* __restrict__ o3, int n4w) {
    const int y = blockIdx.y;
    const float4* in  = y == 0 ? x  : (y == 1 ? w0 : (y == 2 ? w1 : (y == 3 ? w2 : w3)));
    half4_t*      out = y == 0 ? xo : (y == 1 ? o0 : (y == 2 ? o1 : (y == 3 ? o2 : o3)));
    const int n4 = y == 0 ? n4x : n4w;
    for (int i = blockIdx.x * blockDim.x + threadIdx.x; i < n4;
         i += gridDim.x * blockDim.x) {
        const float4 a = in[i];
        half4_t h;
        h[0] = (_Float16)a.x; h[1] = (_Float16)a.y;
        h[2] = (_Float16)a.z; h[3] = (_Float16)a.w;
        out[i] = h;
    }
}

// ---------------- f16 MFMA GEMM, 256x256 tile, BK=64, 4-phase/K-tile ------
// r9 champion schedule (verified) — byte-identical to r12.
template<int MODE, int NTN>
__global__ __launch_bounds__(512)
void gemm8p(const _Float16* __restrict__ A, const _Float16* __restrict__ W,
            const float* __restrict__ B0, const float* __restrict__ B1,
            const float* __restrict__ B2, void* __restrict__ out_base)
{
    constexpr int K  = DMODEL;
    constexpr int nt = K / 64;                   // 16 K-tiles
    const int bid  = blockIdx.x;
    const int nwg8 = (64 * NTN) >> 3;
    const int swz  = (bid & 7) * nwg8 + (bid >> 3);
    const int i0   = (swz / NTN) * 256;
    const int n0   = (swz % NTN) * 256;

    __shared__ _Float16 As[4][128 * 64];         // [parity*2 + half]
    __shared__ _Float16 Bs[4][128 * 64];

    const int tid  = threadIdx.x;
    const int lane = tid & 63;
    const int wid  = tid >> 6;
    const int wr   = wid >> 2;
    const int wc   = wid & 3;
    const int fr   = lane & 15;
    const int fh   = lane >> 4;
    const int sw8  = fr & 7;
    const int ok0  = ((fh) ^ sw8) * 8;
    const int ok1  = ((4 + fh) ^ sw8) * 8;
    const int arow = (wr * 16 + fr) * 64;
    const int brow = (wc * 16 + fr) * 64;

    const int srow = tid >> 3;
    const int ssw  = ((tid & 7) ^ (srow & 7)) << 3;
    const _Float16* baseA = A + (size_t)(i0 + srow) * K + ssw;
    const _Float16* baseB = W + (size_t)(n0 + srow) * K + ssw;
    const int ldso = tid * 8;

    floatx4 acc[8][4];
    #pragma unroll
    for (int mi = 0; mi < 8; ++mi)
        #pragma unroll
        for (int ni = 0; ni < 4; ++ni) acc[mi][ni] = (floatx4)0.f;

    half8 a_lo[4][2], a_hi[4][2], b_lo[2][2], b_hi[2][2];

#define ST_A(TT, H)                                                          \
    do {                                                                     \
        _Float16* d_ = &As[(((TT) & 1) << 1) | (H)][ldso];                   \
        const _Float16* s_ = baseA + (size_t)((H) * 128) * K + (TT) * 64;    \
        gload16(s_, d_);                                                     \
        gload16(s_ + (size_t)64 * K, d_ + 4096);                             \
    } while (0)
#define ST_B(TT, H)                                                          \
    do {                                                                     \
        _Float16* d_ = &Bs[(((TT) & 1) << 1) | (H)][ldso];                   \
        const _Float16* s_ = baseB + (size_t)((H) * 128) * K + (TT) * 64;    \
        gload16(s_, d_);                                                     \
        gload16(s_ + (size_t)64 * K, d_ + 4096);                             \
    } while (0)
#define RD_A(DST, DB, H)                                                     \
    _Pragma("unroll")                                                        \
    for (int mi = 0; mi < 4; ++mi) {                                         \
        DST[mi][0] = *(const half8*)&As[(DB) | (H)][arow + mi * 2048 + ok0]; \
        DST[mi][1] = *(const half8*)&As[(DB) | (H)][arow + mi * 2048 + ok1]; \
    }
#define RD_B(DST, DB, H)                                                     \
    _Pragma("unroll")                                                        \
    for (int ni = 0; ni < 2; ++ni) {                                         \
        DST[ni][0] = *(const half8*)&Bs[(DB) | (H)][brow + ni * 4096 + ok0]; \
        DST[ni][1] = *(const half8*)&Bs[(DB) | (H)][brow + ni * 4096 + ok1]; \
    }
#define MFMA16(MB, NB, AA, BB)                                               \
    __builtin_amdgcn_s_setprio(1);                                           \
    _Pragma("unroll")                                                        \
    for (int kc = 0; kc < 2; ++kc)                                           \
        _Pragma("unroll")                                                    \
        for (int mi = 0; mi < 4; ++mi)                                       \
            _Pragma("unroll")                                                \
            for (int ni = 0; ni < 2; ++ni)                                   \
                acc[MB + mi][NB + ni] = __builtin_amdgcn_mfma_f32_16x16x32_f16( \
                    AA[mi][kc], BB[ni][kc], acc[MB + mi][NB + ni], 0, 0, 0); \
    __builtin_amdgcn_s_setprio(0);
#define PHEND                                                                \
    asm volatile("s_waitcnt lgkmcnt(0)" ::: "memory");                       \
    __builtin_amdgcn_sched_barrier(0);                                       \
    __builtin_amdgcn_s_barrier();

    // ---- prologue: stage t0 + t1 fully; force t0; first lo-frag reads ----
    ST_A(0, 0); ST_B(0, 0); ST_B(0, 1); ST_A(0, 1);
    ST_A(1, 0); ST_B(1, 1); ST_A(1, 1); ST_B(1, 0);
    asm volatile("s_waitcnt vmcnt(8)" ::: "memory");
    __builtin_amdgcn_sched_barrier(0);
    __builtin_amdgcn_s_barrier();
    RD_A(a_lo, 0, 0); RD_B(b_lo, 0, 0);
    asm volatile("s_waitcnt lgkmcnt(0)" ::: "memory");
    __builtin_amdgcn_sched_barrier(0);

    for (int t = 0; t < nt; ++t) {
        const int d2 = (t & 1) << 1;
        const bool st = (t + 2) < nt;
        // ---- P1: q(0,0); reads B1; NO stage (WAR-safe window for A[d2|0]) --
        RD_B(b_hi, d2, 1);
        MFMA16(0, 0, a_lo, b_lo);
        PHEND;
        // ---- P2: q(0,1); reads A1; stage B1(t+2) + A0(t+2) ----
        RD_A(a_hi, d2, 1);
        if (st) { ST_B(t + 2, 1); ST_A(t + 2, 0); }
        MFMA16(0, 2, a_lo, b_hi);
        PHEND;
        // ---- P3: q(1,1); stage A1(t+2) ----
        if (st) ST_A(t + 2, 1);
        MFMA16(4, 2, a_hi, b_hi);
        PHEND;
        // ---- P4: q(1,0) (b_lo kept from P1); stage B0(t+2); vmcnt ----
        if (st) ST_B(t + 2, 0);
        MFMA16(4, 0, a_hi, b_lo);
        if (st) {
            asm volatile("s_waitcnt vmcnt(8)" ::: "memory");
        } else if (t + 1 < nt) {
            asm volatile("s_waitcnt vmcnt(0)" ::: "memory");
        }
        __builtin_amdgcn_sched_barrier(0);
        __builtin_amdgcn_s_barrier();
        // ---- cross-tile q1 fragment reads (tile t+1) ----
        if (t + 1 < nt) {
            const int dn = ((t + 1) & 1) << 1;
            RD_A(a_lo, dn, 0); RD_B(b_lo, dn, 0);
            asm volatile("s_waitcnt lgkmcnt(0)" ::: "memory");
            __builtin_amdgcn_sched_barrier(0);
        }
    }
#undef ST_A
#undef ST_B
#undef RD_A
#undef RD_B
#undef MFMA16
#undef PHEND

    // ---- epilogue: C/D layout col=lane&15, row=(lane>>4)*4+reg ----
    const int z  = (MODE == 0) ? (n0 >> 10) : 0;
    const float* bz = (MODE == 1) ? B0 : (z == 0 ? B0 : (z == 1 ? B1 : B2));

    #pragma unroll
    for (int ni = 0; ni < 4; ++ni) {
        const int gc   = n0 + ni * 64 + wc * 16 + fr;
        const int gcol = gc & (DMODEL - 1);
        const float bv = bz[gcol];
        #pragma unroll
        for (int mi = 0; mi < 8; ++mi) {
            const int gr = i0 + mi * 32 + wr * 16 + fh * 4;
            const floatx4 v = acc[mi][ni];
            if (MODE == 0) {
                _Float16* outh = (_Float16*)out_base
                               + (size_t)z * ((size_t)16384 * DMODEL);
                const int bb = gr >> 12;
                const int sp = gr & (S_LEN - 1);
                const int hh = gcol >> 6;
                const int dh = gcol & 63;
                if (z < 2) {
                    #pragma unroll
                    for (int r = 0; r < 4; ++r)
                        outh[((((size_t)(bb * NHEADS + hh)) * S_LEN + sp + r) << 6) + dh] =
                            (_Float16)(v[r] + bv);
                } else {
                    half4_t hv;
                    hv[0] = (_Float16)(v[0] + bv); hv[1] = (_Float16)(v[1] + bv);
                    hv[2] = (_Float16)(v[2] + bv); hv[3] = (_Float16)(v[3] + bv);
                    *(half4_t*)&outh[(((size_t)(bb * NHEADS + hh)) * DHEAD + dh) * S_LEN + sp] = hv;
                }
            } else {
                float* out = (float*)out_base;
                #pragma unroll
                for (int r = 0; r < 4; ++r)
                    out[(size_t)(gr + r) * DMODEL + gcol] = v[r] + bv;
            }
        }
    }
}

// ---------------- MFMA windowed attention, wave-local exact prefix scan ---
// qh,kh: [B,H,S,Dh] f16; vth: [B,H,Dh,S] f16; o: [B,S,H,Dh] f16.
// Wave w owns S/P rows 16w..16w+15 end-to-end (QK^T -> scan -> PV), so the
// scan is wave-private: scan lane = (sq = 16w + lane>>2, seg = lane&3);
// seg-combine via 4-lane __shfl groups, Mq/Tq carried in registers (same
// max/add ordering as r12 -> bit-identical). Barriers: 2/chunk (stage WAR
// + stage RAW). SP/P16 wave-local => in-wave lgkmcnt(0) only.
__global__ __launch_bounds__(256)
void attn_mfma(const _Float16* __restrict__ qh_, const _Float16* __restrict__ kh_,
               const _Float16* __restrict__ vth_, _Float16* __restrict__ o)
{
    __shared__ __align__(16) _Float16 Qs[64 * 64];
    __shared__ __align__(16) _Float16 Ks[64 * 64];
    __shared__ __align__(16) _Float16 Vt[64 * 64];
    __shared__ __align__(16) float    SP[64 * 68];
    __shared__ __align__(16) _Float16 P16[64 * 64];
    __shared__ float TqL[64];

    const int tid   = threadIdx.x;
    const int lane  = tid & 63;
    const int w     = tid >> 6;
    const int qbase = blockIdx.x * 64;
    const int head  = blockIdx.y, b = blockIdx.z;
    const size_t bh = (size_t)(b * NHEADS + head);

    const _Float16* qg = qh_  + bh * (size_t)(S_LEN * DHEAD);
    const _Float16* kg = kh_  + bh * (size_t)(S_LEN * DHEAD);
    const _Float16* vg = vth_ + bh * (size_t)(DHEAD * S_LEN);

    const int fr  = lane & 15;
    const int fh  = lane >> 4;
    const int sqt = 16 * w + (lane >> 2);   // scan row (wave-local)
    const int sg  = lane & 3;               // 16-key segment
    const int gb  = lane & ~3;              // 4-lane group base

    #pragma unroll
    for (int rep = 0; rep < 2; ++rep) {
        const int c = tid + 256 * rep;
        const int row = c >> 3, sll = c & 7;
        gload16(qg + (size_t)(qbase + row) * 64 + (size_t)((sll ^ (row & 7)) * 8),
                Qs + (size_t)c * 8);
    }

    float mq = -INFINITY;   // running prefix-max carry (register)
    float tq = 0.f;         // running denominator (register)

    floatx4 Oacc[4];
    #pragma unroll
    for (int ni = 0; ni < 4; ++ni) Oacc[ni] = (floatx4)0.f;

    for (int c = 0; c < 5; ++c) {
        const int jlo = qbase - WIN + c * 64;
        if (jlo < 0 || jlo >= S_LEN) continue;
        const int base_rel = jlo - qbase + WIN;

        __syncthreads();   // b0: WAR — all prev readers of Ks/Vt done

        #pragma unroll
        for (int rep = 0; rep < 2; ++rep) {
            const int cc = tid + 256 * rep;
            const int row = cc >> 3, sll = cc & 7;
            gload16(kg + (size_t)(jlo + row) * 64 + (size_t)((sll ^ (row & 7)) * 8),
                    Ks + (size_t)cc * 8);
            gload16(vg + (size_t)row * S_LEN + jlo + (size_t)((sll ^ (row & 7)) * 8),
                    Vt + (size_t)cc * 8);
        }
        __syncthreads();   // b1: RAW — staged K/V (and Qs on c0) visible

        // ---- QK^T: wave w computes S rows 16w..16w+15 -> SP (wave-local) --
        {
            floatx4 acc[4];
            #pragma unroll
            for (int ni = 0; ni < 4; ++ni) acc[ni] = (floatx4)0.f;
            half8 a[2];
            #pragma unroll
            for (int kc = 0; kc < 2; ++kc) {
                const int row = 16 * w + fr;
                a[kc] = *(const half8*)&Qs[row * 64 + ((fh + 4 * kc) ^ (row & 7)) * 8];
            }
            #pragma unroll
            for (int ni = 0; ni < 4; ++ni)
                #pragma unroll
                for (int kc = 0; kc < 2; ++kc) {
                    const int tr = 16 * ni + fr;
                    half8 bf = *(const half8*)&Ks[tr * 64 + ((fh + 4 * kc) ^ (tr & 7)) * 8];
                    acc[ni] = __builtin_amdgcn_mfma_f32_16x16x32_f16(a[kc], bf, acc[ni], 0, 0, 0);
                }
            #pragma unroll
            for (int ni = 0; ni < 4; ++ni)
                #pragma unroll
                for (int r = 0; r < 4; ++r)
                    SP[(16 * w + 4 * fh + r) * 68 + fr + 16 * ni] = acc[ni][r] * 0.125f;
        }
        // in-wave: SP writes -> scan reads
        asm volatile("s_waitcnt lgkmcnt(0)" ::: "memory");
        __builtin_amdgcn_sched_barrier(0);

        // ---- scan (wave-private, exact r12 semantics) ----
        {
            float sv[16], run[16];
            float m_run = -INFINITY;
            #pragma unroll
            for (int u = 0; u < 4; ++u) {
                const float4 s4 = *(const float4*)&SP[sqt * 68 + sg * 16 + 4 * u];
                const float se[4] = {s4.x, s4.y, s4.z, s4.w};
                #pragma unroll
                for (int e = 0; e < 4; ++e) {
                    const int i = 4 * u + e;
                    const int rel = base_rel + sg * 16 + i - sqt;
                    const bool valid = (rel >= 0) && (rel <= 2 * WIN);
                    const float s = valid ? se[e] : -INFINITY;
                    sv[i] = s;
                    m_run = fmaxf(m_run, s);
                    run[i] = m_run;
                }
            }
            const float cm = m_run;
            const float c0 = __shfl(cm, gb + 0);
            const float c1 = __shfl(cm, gb + 1);
            const float c2 = __shfl(cm, gb + 2);
            const float c3 = __shfl(cm, gb + 3);
            float pre = mq;
            if (sg > 0) pre = fmaxf(pre, c0);
            if (sg > 1) pre = fmaxf(pre, c1);
            if (sg > 2) pre = fmaxf(pre, c2);

            float tl = 0.f;
            _Float16 pf[16];
            #pragma unroll
            for (int i = 0; i < 16; ++i) {
                const float wm = fmaxf(pre, run[i]);
                const float p = (sv[i] != -INFINITY) ? __expf(sv[i] - wm) : 0.f;
                tl += p;
                pf[i] = (_Float16)p;
            }
            #pragma unroll
            for (int u = 0; u < 2; ++u) {
                half8 h8;
                #pragma unroll
                for (int e = 0; e < 8; ++e) h8[e] = pf[8 * u + e];
                *(half8*)&P16[sqt * 64 + ((2 * sg + u) ^ (sqt & 7)) * 8] = h8;
            }
            // carries (registers; same combine order as r12)
            const float t0 = __shfl(tl, gb + 0);
            const float t1 = __shfl(tl, gb + 1);
            const float t2 = __shfl(tl, gb + 2);
            const float t3 = __shfl(tl, gb + 3);
            tq += t0 + t1 + t2 + t3;
            mq = fmaxf(mq, fmaxf(fmaxf(c0, c1), fmaxf(c2, c3)));
        }
        // in-wave: P16 writes -> PV reads (rows 16w..16w+15, wave-local)
        asm volatile("s_waitcnt lgkmcnt(0)" ::: "memory");
        __builtin_amdgcn_sched_barrier(0);

        // ---- PV: Oacc[ni] += P[16w..][t] * V[t][16ni..] ----
        {
            half8 pa[2];
            #pragma unroll
            for (int kc = 0; kc < 2; ++kc) {
                const int row = 16 * w + fr;
                pa[kc] = *(const half8*)&P16[row * 64 + ((fh + 4 * kc) ^ (row & 7)) * 8];
            }
            #pragma unroll
            for (int ni = 0; ni < 4; ++ni)
                #pragma unroll
                for (int kc = 0; kc < 2; ++kc) {
                    const int dr = 16 * ni + fr;
                    half8 bf = *(const half8*)&Vt[dr * 64 + ((fh + 4 * kc) ^ (dr & 7)) * 8];
                    Oacc[ni] = __builtin_amdgcn_mfma_f32_16x16x32_f16(pa[kc], bf, Oacc[ni], 0, 0, 0);
                }
        }
    }

    // ---- epilogue: Tq to LDS (wave-local rows), then O/Tq -> o ----
    if (sg == 0) TqL[sqt] = tq;
    asm volatile("s_waitcnt lgkmcnt(0)" ::: "memory");
    __builtin_amdgcn_sched_barrier(0);

    #pragma unroll
    for (int ni = 0; ni < 4; ++ni)
        #pragma unroll
        for (int r = 0; r < 4; ++r) {
            const int q  = 16 * w + 4 * fh + r;
            const float inv = 1.0f / TqL[q];
            o[((size_t)(b * S_LEN + qbase + q) * NHEADS + head) * DHEAD + fr + 16 * ni] =
                (_Float16)(Oacc[ni][r] * inv);
        }
}

extern "C" void kernel_launch(void* const* d_in, const int* in_sizes, int n_in,
                              void* d_out, int out_size, void* d_ws, size_t ws_size,
                              hipStream_t stream) {
    const float* x  = (const float*)d_in[0];
    const float* wq = (const float*)d_in[1];
    const float* bq = (const float*)d_in[2];
    const float* wk = (const float*)d_in[3];
    const float* bk = (const float*)d_in[4];
    const float* wv = (const float*)d_in[5];
    const float* bv = (const float*)d_in[6];
    const float* wo = (const float*)d_in[7];
    const float* bo = (const float*)d_in[8];

    const size_t BUF = (size_t)BATCH * S_LEN * DMODEL;   // 16,777,216 elems
    _Float16* xh  = (_Float16*)d_ws;
    _Float16* qh  = xh + BUF;
    _Float16* kh  = qh + BUF;       // qh/kh/vth consecutive (z-slab offset)
    _Float16* vth = kh + BUF;
    _Float16* oh  = vth + BUF;
    _Float16* wqh = oh + BUF;       // wqh/wkh/wvh consecutive = W_all [3072,1024]
    _Float16* wkh = wqh + DMODEL * DMODEL;
    _Float16* wvh = wkh + DMODEL * DMODEL;
    _Float16* woh = wvh + DMODEL * DMODEL;

    // 1) fp32 -> f16 conversions (single launch; y=0 x, y=1..4 weights)
    cvt5_f32_f16<<<dim3(512, 5), 256, 0, stream>>>(
        (const float4*)x, (half4_t*)xh, (int)(BUF / 4),
        (const float4*)wq, (const float4*)wk, (const float4*)wv, (const float4*)wo,
        (half4_t*)wqh, (half4_t*)wkh, (half4_t*)wvh, (half4_t*)woh,
        DMODEL * DMODEL / 4);

    // 2) fused QKV projection: [16384,1024] @ [3072,1024]^T
    gemm8p<0, 12><<<64 * 12, 512, 0, stream>>>(xh, wqh, bq, bk, bv, (void*)qh);

    // 3) MFMA windowed attention -> oh f16 [B,S,H,Dh]
    dim3 gattn(S_LEN / 64, NHEADS, BATCH);
    attn_mfma<<<gattn, 256, 0, stream>>>(qh, kh, vth, oh);

    // 4) output projection -> fp32 d_out
    gemm8p<1, 4><<<64 * 4, 512, 0, stream>>>(oh, woh, bo, bo, bo, d_out);
}